// Round 1
// 1491.543 us; speedup vs baseline: 2.5412x; 2.5412x over previous
//
#include <hip/hip_runtime.h>
#include <math.h>

#define NTHREADS 256
#define IN_C 128
#define HID 64
#define OUT_C 40
#define N_LAYERS 8
#define ALPHA 0.1f
#define BN_EPS 1e-5f

typedef float f32x4 __attribute__((ext_vector_type(4)));

__device__ __forceinline__ f32x4 ld4(const float* p) { return *(const f32x4*)p; }

// fused BN + ReLU: relu(v*k1 + k2). For layer 0, k1=1,k2=0 -> relu(h)=h (h>=0).
__device__ __forceinline__ f32x4 bnrelu(f32x4 v, f32x4 k1, f32x4 k2) {
  f32x4 r = v * k1 + k2;
  r.x = fmaxf(r.x, 0.f); r.y = fmaxf(r.y, 0.f);
  r.z = fmaxf(r.z, 0.f); r.w = fmaxf(r.w, 0.f);
  return r;
}

// reduce across the 4 replicated 16-lane groups (lanes l, l+16, l+32, l+48)
__device__ __forceinline__ f32x4 xreduce(f32x4 v) {
  v.x += __shfl_xor(v.x, 16); v.y += __shfl_xor(v.y, 16);
  v.z += __shfl_xor(v.z, 16); v.w += __shfl_xor(v.w, 16);
  v.x += __shfl_xor(v.x, 32); v.y += __shfl_xor(v.y, 32);
  v.z += __shfl_xor(v.z, 32); v.w += __shfl_xor(v.w, 32);
  return v;
}

// ---------------- setup kernels ----------------

__global__ void k_zero(int* __restrict__ cnt, float* __restrict__ sumP,
                       float* __restrict__ sumsqP, float* __restrict__ mstat,
                       int2* __restrict__ ewpad, int n) {
  int i = blockIdx.x * NTHREADS + threadIdx.x;
  if (i < n) cnt[i] = 0;
  if (i < 1024) { sumP[i] = 0.f; sumsqP[i] = 0.f; }
  if (i < 64) { mstat[i] = 1.f; mstat[64 + i] = 0.f; }  // identity BN for layer 0
  if (i < 16) ewpad[i] = make_int2(0, 0);               // tail-safe pad records
}

__global__ void k_hist(const int* __restrict__ col, int* __restrict__ cnt, int E) {
  int e = blockIdx.x * NTHREADS + threadIdx.x;
  if (e < E) atomicAdd(&cnt[col[e]], 1);
}

__global__ void k_dinv(const int* __restrict__ cnt, float* __restrict__ dinv, int n) {
  int i = blockIdx.x * NTHREADS + threadIdx.x;
  if (i < n) dinv[i] = rsqrtf((float)cnt[i] + 1.0f);
}

__global__ void k_scan1(const int* __restrict__ cnt, int* __restrict__ offs,
                        int* __restrict__ partials, int n) {
  __shared__ int sh[NTHREADS];
  int t = threadIdx.x, i = blockIdx.x * NTHREADS + t;
  int v = (i < n) ? cnt[i] : 0;
  sh[t] = v;
  __syncthreads();
  int run = v;
  for (int d = 1; d < NTHREADS; d <<= 1) {
    int add = (t >= d) ? sh[t - d] : 0;
    __syncthreads();
    run += add;
    sh[t] = run;
    __syncthreads();
  }
  if (i < n) offs[i] = run - v;
  if (t == NTHREADS - 1) partials[blockIdx.x] = run;
}

__global__ void k_scan2(int* __restrict__ partials, int nb) {
  __shared__ int sh[512];
  int t = threadIdx.x;
  int v = (t < nb) ? partials[t] : 0;
  sh[t] = v;
  __syncthreads();
  int run = v;
  for (int d = 1; d < 512; d <<= 1) {
    int add = (t >= d) ? sh[t - d] : 0;
    __syncthreads();
    run += add;
    sh[t] = run;
    __syncthreads();
  }
  if (t < nb) partials[t] = run - v;
}

__global__ void k_scan3(int* __restrict__ offs, int* __restrict__ cur,
                        const int* __restrict__ partials, int n, int E) {
  int i = blockIdx.x * NTHREADS + threadIdx.x;
  if (i < n) {
    int v = offs[i] + partials[i >> 8];
    offs[i] = v;
    cur[i] = v;
  }
  if (i == 0) offs[n] = E;
}

__global__ void k_fill(const int* __restrict__ row, const int* __restrict__ col,
                       const float* __restrict__ dinv, int* __restrict__ cur,
                       int2* __restrict__ ew, int E) {
  int e = blockIdx.x * NTHREADS + threadIdx.x;
  if (e < E) {
    int cl = col[e];
    int rw = row[e];
    int pos = atomicAdd(&cur[cl], 1);
    ew[pos] = make_int2(rw, __float_as_int(dinv[rw]));
  }
}

// ---------------- h = relu(x @ W0 + b0); also h0 = h ----------------
__global__ __launch_bounds__(NTHREADS) void k_gemm0(
    const float* __restrict__ x, const float* __restrict__ W0,
    const float* __restrict__ b0, float* __restrict__ h, float* __restrict__ h0,
    int n) {
  __shared__ float Ws[IN_C * HID];
  __shared__ float xs[8 * IN_C];
  int t = threadIdx.x;
  for (int m = t; m < IN_C * HID / 4; m += NTHREADS)
    ((float4*)Ws)[m] = ((const float4*)W0)[m];
  int gi = blockIdx.x * 256 + t;
  if (gi * 4 < n * IN_C) ((float4*)xs)[t] = ((const float4*)x)[gi];
  __syncthreads();
  int ty = t >> 6, c = t & 63;
  int r0 = blockIdx.x * 8 + ty * 2;
  float bias = b0[c];
  float acc0 = bias, acc1 = bias;
  const float4* xr0 = (const float4*)(xs + (ty * 2) * IN_C);
  const float4* xr1 = (const float4*)(xs + (ty * 2 + 1) * IN_C);
  for (int kk = 0; kk < IN_C / 4; kk++) {
    float4 a0 = xr0[kk], a1 = xr1[kk];
    int k = kk * 4;
    float w0 = Ws[(k + 0) * HID + c], w1 = Ws[(k + 1) * HID + c];
    float w2 = Ws[(k + 2) * HID + c], w3 = Ws[(k + 3) * HID + c];
    acc0 += a0.x * w0 + a0.y * w1 + a0.z * w2 + a0.w * w3;
    acc1 += a1.x * w0 + a1.y * w1 + a1.z * w2 + a1.w * w3;
  }
  acc0 = fmaxf(acc0, 0.f);
  acc1 = fmaxf(acc1, 0.f);
  if (r0 < n)     { h[(size_t)r0 * HID + c] = acc0; h0[(size_t)r0 * HID + c] = acc0; }
  if (r0 + 1 < n) { h[(size_t)(r0 + 1) * HID + c] = acc1; h0[(size_t)(r0 + 1) * HID + c] = acc1; }
}

// ---------------- fused layer ----------------
// Lane layout: 16 lanes x float4 per row; 4 lane-groups process 4 edges in
// parallel (dwordx4 gather). BN+ReLU of the PREVIOUS layer is applied inline
// to every gathered row (k1/k2 from mstat), so no separate bnapply pass and
// no materialized h. Conv is split-K across the 4 groups via width-16
// shuffles; waves are fully independent (no per-iteration barriers).
// Stores are 16 x b128 = full-line bursts (kills the x32 write amplification).
__global__ __launch_bounds__(NTHREADS, 4) void k_layer(
    const float* __restrict__ hin, const float* __restrict__ h0,
    const float* __restrict__ dinv, const int* __restrict__ offs,
    const int2* __restrict__ ew, const float* __restrict__ Wl,
    const float* __restrict__ mstat, float* __restrict__ sout,
    float* __restrict__ sumP, float* __restrict__ sumsqP, float beta, int n) {
  __shared__ __align__(16) float Wsh[HID * HID];  // 16 KB
  __shared__ f32x4 red4[2][4][16];                // 2 KB
  int t = threadIdx.x;
  for (int m = t; m < HID * HID / 4; m += NTHREADS)
    ((f32x4*)Wsh)[m] = ((const f32x4*)Wl)[m];
  int wid = t >> 6, lane = t & 63;
  int eg = lane >> 4, li = lane & 15, c4 = li << 2;
  f32x4 k1 = ld4(mstat + c4);
  f32x4 k2 = ld4(mstat + 64 + c4);
  __syncthreads();
  f32x4 lsum = {0.f, 0.f, 0.f, 0.f}, lsumsq = {0.f, 0.f, 0.f, 0.f};
  const long long* ew8 = (const long long*)ew;
  int stride = gridDim.x * 16;
  for (int base = blockIdx.x * 16; base < n; base += stride) {
    int i0 = base + wid * 4;
    for (int r = 0; r < 4; r++) {
      int i = i0 + r;
      if (i >= n) break;
      int jb = offs[i], je = offs[i + 1];
      float di = dinv[i];
      // issue self + residual loads early (overlap with edge latency)
      f32x4 hs_raw = ld4(hin + (size_t)i * HID + c4);
      f32x4 h0v = __builtin_nontemporal_load((const f32x4*)(h0 + (size_t)i * HID + c4));
      f32x4 acc = {0.f, 0.f, 0.f, 0.f};
      int j = jb;
      // full 16-edge blocks: group eg owns edges [j+4*eg, j+4*eg+4)
      for (; j + 16 <= je; j += 16) {
        int mb = j + 4 * eg;
        long long q0 = __builtin_nontemporal_load(ew8 + mb + 0);
        long long q1 = __builtin_nontemporal_load(ew8 + mb + 1);
        long long q2 = __builtin_nontemporal_load(ew8 + mb + 2);
        long long q3 = __builtin_nontemporal_load(ew8 + mb + 3);
        f32x4 v0 = ld4(hin + (size_t)(int)q0 * HID + c4);
        f32x4 v1 = ld4(hin + (size_t)(int)q1 * HID + c4);
        f32x4 v2 = ld4(hin + (size_t)(int)q2 * HID + c4);
        f32x4 v3 = ld4(hin + (size_t)(int)q3 * HID + c4);
        acc += __int_as_float((int)(q0 >> 32)) * bnrelu(v0, k1, k2);
        acc += __int_as_float((int)(q1 >> 32)) * bnrelu(v1, k1, k2);
        acc += __int_as_float((int)(q2 >> 32)) * bnrelu(v2, k1, k2);
        acc += __int_as_float((int)(q3 >> 32)) * bnrelu(v3, k1, k2);
      }
      // tail (< 16 edges): record loads may read past je (pad-safe); h-loads guarded
      if (j < je) {
        int mb = j + 4 * eg;
        long long q0 = ew8[mb + 0], q1 = ew8[mb + 1];
        long long q2 = ew8[mb + 2], q3 = ew8[mb + 3];
        if (mb + 0 < je) {
          f32x4 v = ld4(hin + (size_t)(int)q0 * HID + c4);
          acc += __int_as_float((int)(q0 >> 32)) * bnrelu(v, k1, k2);
        }
        if (mb + 1 < je) {
          f32x4 v = ld4(hin + (size_t)(int)q1 * HID + c4);
          acc += __int_as_float((int)(q1 >> 32)) * bnrelu(v, k1, k2);
        }
        if (mb + 2 < je) {
          f32x4 v = ld4(hin + (size_t)(int)q2 * HID + c4);
          acc += __int_as_float((int)(q2 >> 32)) * bnrelu(v, k1, k2);
        }
        if (mb + 3 < je) {
          f32x4 v = ld4(hin + (size_t)(int)q3 * HID + c4);
          acc += __int_as_float((int)(q3 >> 32)) * bnrelu(v, k1, k2);
        }
      }
      acc = xreduce(acc);  // after this, replicated across the 4 groups
      f32x4 hs = bnrelu(hs_raw, k1, k2);
      f32x4 agg = di * acc + (di * di) * hs;
      f32x4 sval = (1.f - ALPHA) * agg + ALPHA * h0v;
      // split-K conv: group eg computes k in [16*eg, 16*eg+16)
      f32x4 ta = {0.f, 0.f, 0.f, 0.f};
#pragma unroll
      for (int u = 0; u < 4; u++) {
        int kk = 4 * eg + u;
        f32x4 s4;
        s4.x = __shfl(sval.x, kk, 16);
        s4.y = __shfl(sval.y, kk, 16);
        s4.z = __shfl(sval.z, kk, 16);
        s4.w = __shfl(sval.w, kk, 16);
        const f32x4* Wr = (const f32x4*)(Wsh + 4 * kk * HID);
        ta += s4.x * Wr[li] + s4.y * Wr[16 + li] + s4.z * Wr[32 + li] +
              s4.w * Wr[48 + li];
      }
      ta = xreduce(ta);
      f32x4 s2 = (1.f - beta) * sval + beta * ta;
      lsum += s2;        // replicated x4; only group 0's copy is reduced below
      lsumsq += s2 * s2;
      if (eg == 0)
        __builtin_nontemporal_store(s2, (f32x4*)(sout + (size_t)i * HID + c4));
    }
  }
  if (eg == 0) { red4[0][wid][li] = lsum; red4[1][wid][li] = lsumsq; }
  __syncthreads();
  if (t < 16) {
    f32x4 a = red4[0][0][li] + red4[0][1][li] + red4[0][2][li] + red4[0][3][li];
    f32x4 b = red4[1][0][li] + red4[1][1][li] + red4[1][2][li] + red4[1][3][li];
    atomicAdd(&sumP[(c4 + 0) * 16], a.x);
    atomicAdd(&sumP[(c4 + 1) * 16], a.y);
    atomicAdd(&sumP[(c4 + 2) * 16], a.z);
    atomicAdd(&sumP[(c4 + 3) * 16], a.w);
    atomicAdd(&sumsqP[(c4 + 0) * 16], b.x);
    atomicAdd(&sumsqP[(c4 + 1) * 16], b.y);
    atomicAdd(&sumsqP[(c4 + 2) * 16], b.z);
    atomicAdd(&sumsqP[(c4 + 3) * 16], b.w);
  }
}

// mean/inv-std -> affine form k1 = iv*gamma, k2 = beta - mu*k1; resets sums
__global__ void k_finalize(float* __restrict__ sumP, float* __restrict__ sumsqP,
                           float* __restrict__ mstat,
                           const float* __restrict__ gamma_l,
                           const float* __restrict__ beta_l, int n) {
  int c = threadIdx.x;  // 64 threads
  float s = sumP[c * 16], sq = sumsqP[c * 16];
  float mu = s / (float)n;
  float var = sq / (float)n - mu * mu;
  float iv = rsqrtf(var + BN_EPS);
  float kk1 = iv * gamma_l[c];
  mstat[c] = kk1;
  mstat[64 + c] = beta_l[c] - mu * kk1;
  sumP[c * 16] = 0.f;
  sumsqP[c * 16] = 0.f;
}

// final h = relu(s*k1 + k2) before the output GEMM
__global__ void k_bnfinal(const float* __restrict__ s,
                          const float* __restrict__ mstat,
                          float* __restrict__ h, int n) {
  int idx = blockIdx.x * NTHREADS + threadIdx.x;  // f32x4 index
  if (idx < n * (HID / 4)) {
    int c4 = idx & 15;
    f32x4 v = ((const f32x4*)s)[idx];
    f32x4 k1 = ((const f32x4*)mstat)[c4];
    f32x4 k2 = ((const f32x4*)(mstat + 64))[c4];
    v = v * k1 + k2;
    v.x = fmaxf(v.x, 0.f); v.y = fmaxf(v.y, 0.f);
    v.z = fmaxf(v.z, 0.f); v.w = fmaxf(v.w, 0.f);
    ((f32x4*)h)[idx] = v;
  }
}

// out = h @ W_out + b_out
__global__ __launch_bounds__(NTHREADS) void k_out(
    const float* __restrict__ h, const float* __restrict__ Wout,
    const float* __restrict__ bout, float* __restrict__ out, int n) {
  __shared__ float Ws[HID * OUT_C];
  __shared__ float bs[OUT_C];
  int t = threadIdx.x;
  for (int m = t; m < HID * OUT_C; m += NTHREADS) Ws[m] = Wout[m];
  if (t < OUT_C) bs[t] = bout[t];
  __syncthreads();
  int idx = blockIdx.x * NTHREADS + t;
  if (idx < n * OUT_C) {
    int row = idx / OUT_C;
    int c = idx - row * OUT_C;
    float acc = bs[c];
    const float4* h4 = (const float4*)(h + (size_t)row * HID);
    for (int kk = 0; kk < HID / 4; kk++) {
      float4 a = h4[kk];
      int k = kk * 4;
      acc += a.x * Ws[(k + 0) * OUT_C + c] + a.y * Ws[(k + 1) * OUT_C + c] +
             a.z * Ws[(k + 2) * OUT_C + c] + a.w * Ws[(k + 3) * OUT_C + c];
    }
    out[idx] = acc;
  }
}

// ---------------- host ----------------

extern "C" void kernel_launch(void* const* d_in, const int* in_sizes, int n_in,
                              void* d_out, int out_size, void* d_ws, size_t ws_size,
                              hipStream_t stream) {
  const float* x = (const float*)d_in[0];
  const int* ei = (const int*)d_in[1];
  const float* W0 = (const float*)d_in[2];
  const float* b0 = (const float*)d_in[3];
  const float* convW = (const float*)d_in[4];
  const float* bn_gamma = (const float*)d_in[5];
  const float* bn_beta = (const float*)d_in[6];
  const float* W_out = (const float*)d_in[7];
  const float* b_out = (const float*)d_in[8];
  float* out = (float*)d_out;

  int n = in_sizes[0] / IN_C;   // 100000
  int E = in_sizes[1] / 2;      // 1600000
  const int* row = ei;
  const int* col = ei + E;

  char* w = (char*)d_ws;
  auto alloc = [&](size_t bytes) {
    char* p = w;
    w += (bytes + 255) & ~(size_t)255;
    return p;
  };
  float* dinv    = (float*)alloc((size_t)n * 4);
  int*   cnt     = (int*)alloc((size_t)n * 4);
  int*   offs    = (int*)alloc((size_t)(n + 1) * 4);
  int*   cur     = (int*)alloc((size_t)n * 4);
  int*   partials= (int*)alloc(512 * 4);
  int2*  ew      = (int2*)alloc((size_t)(E + 16) * 8);  // +16 pad records
  float* h0b     = (float*)alloc((size_t)n * HID * 4);
  float* hb      = (float*)alloc((size_t)n * HID * 4);  // ping (gemm0 out / odd-layer out)
  float* sb      = (float*)alloc((size_t)n * HID * 4);  // pong (even-layer out)
  float* sumP    = (float*)alloc(1024 * 4);
  float* sumsqP  = (float*)alloc(1024 * 4);
  float* mstat   = (float*)alloc(128 * 4);

  int gN = (n + NTHREADS - 1) / NTHREADS;   // 391
  int gE = (E + NTHREADS - 1) / NTHREADS;   // 6250

  k_zero<<<gN, NTHREADS, 0, stream>>>(cnt, sumP, sumsqP, mstat, ew + E, n);
  k_hist<<<gE, NTHREADS, 0, stream>>>(col, cnt, E);
  k_dinv<<<gN, NTHREADS, 0, stream>>>(cnt, dinv, n);
  k_scan1<<<gN, NTHREADS, 0, stream>>>(cnt, offs, partials, n);
  k_scan2<<<1, 512, 0, stream>>>(partials, gN);
  k_scan3<<<gN, NTHREADS, 0, stream>>>(offs, cur, partials, n, E);
  k_fill<<<gE, NTHREADS, 0, stream>>>(row, col, dinv, cur, ew, E);

  k_gemm0<<<(n + 7) / 8, NTHREADS, 0, stream>>>(x, W0, b0, hb, h0b, n);

  // layer l: input = (l odd ? sb : hb) with BN_{l-1} fused (mstat),
  //          output s_l = (l odd ? hb : sb); stats -> mstat for next layer
  for (int l = 0; l < N_LAYERS; l++) {
    float beta = logf(0.5f / (float)(l + 1) + 1.0f);
    const float* inp = (l & 1) ? sb : hb;
    float* outp = (l & 1) ? hb : sb;
    k_layer<<<2048, NTHREADS, 0, stream>>>(inp, h0b, dinv, offs, ew,
                                           convW + (size_t)l * HID * HID, mstat,
                                           outp, sumP, sumsqP, beta, n);
    k_finalize<<<1, 64, 0, stream>>>(sumP, sumsqP, mstat,
                                     bn_gamma + l * HID, bn_beta + l * HID, n);
  }

  // s_7 lives in hb; materialize h = relu(BN_7(s_7)) once, then output GEMM
  k_bnfinal<<<(n * (HID / 4) + NTHREADS - 1) / NTHREADS, NTHREADS, 0, stream>>>(
      hb, mstat, sb, n);
  k_out<<<((size_t)n * OUT_C + NTHREADS - 1) / NTHREADS, NTHREADS, 0, stream>>>(
      sb, W_out, b_out, out, n);
}

// Round 2
// 1354.893 us; speedup vs baseline: 2.7975x; 1.1009x over previous
//
#include <hip/hip_runtime.h>
#include <math.h>

#define NTHREADS 256
#define IN_C 128
#define HID 64
#define OUT_C 40
#define N_LAYERS 8
#define ALPHA 0.1f
#define BN_EPS 1e-5f

typedef float f32x4 __attribute__((ext_vector_type(4)));
typedef _Float16 f16;
typedef _Float16 f16x4 __attribute__((ext_vector_type(4)));

__device__ __forceinline__ f32x4 ld4(const float* p) { return *(const f32x4*)p; }

// fp16 row load + widen
__device__ __forceinline__ f32x4 ldh4(const f16* p) {
  f16x4 v = *(const f16x4*)p;
  return __builtin_convertvector(v, f32x4);
}

// fused BN + ReLU: relu(v*k1 + k2). Layer 0 uses identity k1=1,k2=0.
__device__ __forceinline__ f32x4 bnrelu(f32x4 v, f32x4 k1, f32x4 k2) {
  f32x4 r = v * k1 + k2;
  r.x = fmaxf(r.x, 0.f); r.y = fmaxf(r.y, 0.f);
  r.z = fmaxf(r.z, 0.f); r.w = fmaxf(r.w, 0.f);
  return r;
}

// reduce across the 4 replicated 16-lane groups
__device__ __forceinline__ f32x4 xreduce(f32x4 v) {
  v.x += __shfl_xor(v.x, 16); v.y += __shfl_xor(v.y, 16);
  v.z += __shfl_xor(v.z, 16); v.w += __shfl_xor(v.w, 16);
  v.x += __shfl_xor(v.x, 32); v.y += __shfl_xor(v.y, 32);
  v.z += __shfl_xor(v.z, 32); v.w += __shfl_xor(v.w, 32);
  return v;
}

__device__ __forceinline__ float bcast(float v, int lane) {
  return __int_as_float(__builtin_amdgcn_readlane(__float_as_int(v), lane));
}

// ---------------- setup kernels ----------------

__global__ void k_zero(int* __restrict__ cnt, float* __restrict__ sumP,
                       float* __restrict__ sumsqP, float* __restrict__ mstat,
                       int2* __restrict__ ewpad, int n) {
  int i = blockIdx.x * NTHREADS + threadIdx.x;
  if (i < n) cnt[i] = 0;
  if (i < 1024) { sumP[i] = 0.f; sumsqP[i] = 0.f; }
  if (i < 64) { mstat[i] = 1.f; mstat[64 + i] = 0.f; }  // identity BN for layer 0
  if (i < 16) ewpad[i] = make_int2(0, 0);               // tail-safe pad records
}

__global__ void k_hist(const int* __restrict__ col, int* __restrict__ cnt, int E) {
  int e = blockIdx.x * NTHREADS + threadIdx.x;
  if (e < E) atomicAdd(&cnt[col[e]], 1);
}

__global__ void k_dinv(const int* __restrict__ cnt, float* __restrict__ dinv, int n) {
  int i = blockIdx.x * NTHREADS + threadIdx.x;
  if (i < n) dinv[i] = rsqrtf((float)cnt[i] + 1.0f);
}

__global__ void k_scan1(const int* __restrict__ cnt, int* __restrict__ offs,
                        int* __restrict__ partials, int n) {
  __shared__ int sh[NTHREADS];
  int t = threadIdx.x, i = blockIdx.x * NTHREADS + t;
  int v = (i < n) ? cnt[i] : 0;
  sh[t] = v;
  __syncthreads();
  int run = v;
  for (int d = 1; d < NTHREADS; d <<= 1) {
    int add = (t >= d) ? sh[t - d] : 0;
    __syncthreads();
    run += add;
    sh[t] = run;
    __syncthreads();
  }
  if (i < n) offs[i] = run - v;
  if (t == NTHREADS - 1) partials[blockIdx.x] = run;
}

__global__ void k_scan2(int* __restrict__ partials, int nb) {
  __shared__ int sh[512];
  int t = threadIdx.x;
  int v = (t < nb) ? partials[t] : 0;
  sh[t] = v;
  __syncthreads();
  int run = v;
  for (int d = 1; d < 512; d <<= 1) {
    int add = (t >= d) ? sh[t - d] : 0;
    __syncthreads();
    run += add;
    sh[t] = run;
    __syncthreads();
  }
  if (t < nb) partials[t] = run - v;
}

__global__ void k_scan3(int* __restrict__ offs, int* __restrict__ cur,
                        const int* __restrict__ partials, int n, int E) {
  int i = blockIdx.x * NTHREADS + threadIdx.x;
  if (i < n) {
    int v = offs[i] + partials[i >> 8];
    offs[i] = v;
    cur[i] = v;
  }
  if (i == 0) offs[n] = E;
}

__global__ void k_fill(const int* __restrict__ row, const int* __restrict__ col,
                       const float* __restrict__ dinv, int* __restrict__ cur,
                       int2* __restrict__ ew, int E) {
  int e = blockIdx.x * NTHREADS + threadIdx.x;
  if (e < E) {
    int cl = col[e];
    int rw = row[e];
    int pos = atomicAdd(&cur[cl], 1);
    ew[pos] = make_int2(rw, __float_as_int(dinv[rw]));
  }
}

// ---------------- h0 = relu(x @ W0 + b0), fp16 out ----------------
// No LDS. W column in 128 VGPRs; each wave loads 2 x-rows coalesced into
// registers (32 lanes x float4 = one 128-float row) and broadcasts x[k] via
// v_readlane (VALU pipe). Inner loop = readlane + fmac, fully unrolled.
__global__ __launch_bounds__(NTHREADS) void k_gemm0(
    const float* __restrict__ x, const float* __restrict__ W0,
    const float* __restrict__ b0, f16* __restrict__ h016, int n) {
  int t = threadIdx.x;
  int lane = t & 63;
  int c = lane;
  float Wc[IN_C];
#pragma unroll
  for (int k = 0; k < IN_C; k++) Wc[k] = W0[k * HID + c];
  float bias = b0[c];
  int half = lane >> 5, li = lane & 31;
  int wg = blockIdx.x * (NTHREADS / 64) + (t >> 6);
  int NW = gridDim.x * (NTHREADS / 64);
  int npairs = (n + 1) >> 1;
  for (int p = wg; p < npairs; p += NW) {
    int r = 2 * p + half;
    f32x4 xv = {0.f, 0.f, 0.f, 0.f};
    if (r < n) xv = ld4(x + (size_t)r * IN_C + li * 4);
    float acc0 = bias, acc1 = bias;
#pragma unroll
    for (int k = 0; k < IN_C; k++) {
      int sl = k >> 2;
      float comp = xv[k & 3];
      float a0 = bcast(comp, sl);
      float a1 = bcast(comp, 32 + sl);
      acc0 += a0 * Wc[k];
      acc1 += a1 * Wc[k];
    }
    acc0 = fmaxf(acc0, 0.f);
    acc1 = fmaxf(acc1, 0.f);
    if (2 * p < n)     h016[(size_t)(2 * p) * HID + c]     = (f16)acc0;
    if (2 * p + 1 < n) h016[(size_t)(2 * p + 1) * HID + c] = (f16)acc1;
  }
}

// ---------------- fused layer (fp16 h-streams) ----------------
// 16 lanes x f16x4 per row (128 B rows): gather loads are dwordx2; BN+ReLU of
// the previous layer fused via k1/k2; conv split-K over the 4 lane-groups;
// stats in fp32; output stored fp16.
__global__ __launch_bounds__(NTHREADS, 5) void k_layer(
    const f16* __restrict__ hin, const f16* __restrict__ h0,
    const float* __restrict__ dinv, const int* __restrict__ offs,
    const int2* __restrict__ ew, const float* __restrict__ Wl,
    const float* __restrict__ mstat, f16* __restrict__ sout,
    float* __restrict__ sumP, float* __restrict__ sumsqP, float beta, int n) {
  __shared__ __align__(16) float Wsh[HID * HID];  // 16 KB
  __shared__ f32x4 red4[2][4][16];                // 2 KB
  int t = threadIdx.x;
  for (int m = t; m < HID * HID / 4; m += NTHREADS)
    ((f32x4*)Wsh)[m] = ((const f32x4*)Wl)[m];
  int wid = t >> 6, lane = t & 63;
  int eg = lane >> 4, li = lane & 15, c4 = li << 2;
  f32x4 k1 = ld4(mstat + c4);
  f32x4 k2 = ld4(mstat + 64 + c4);
  __syncthreads();
  f32x4 lsum = {0.f, 0.f, 0.f, 0.f}, lsumsq = {0.f, 0.f, 0.f, 0.f};
  const long long* ew8 = (const long long*)ew;
  int stride = gridDim.x * 16;
  for (int base = blockIdx.x * 16; base < n; base += stride) {
    int i0 = base + wid * 4;
    for (int r = 0; r < 4; r++) {
      int i = i0 + r;
      if (i >= n) break;
      int jb = offs[i], je = offs[i + 1];
      float di = dinv[i];
      // issue self + residual loads early
      f16x4 hs16 = *(const f16x4*)(hin + (size_t)i * HID + c4);
      f16x4 h016v = __builtin_nontemporal_load((const f16x4*)(h0 + (size_t)i * HID + c4));
      f32x4 acc = {0.f, 0.f, 0.f, 0.f};
      int j = jb;
      for (; j + 16 <= je; j += 16) {
        int mb = j + 4 * eg;
        long long q0 = __builtin_nontemporal_load(ew8 + mb + 0);
        long long q1 = __builtin_nontemporal_load(ew8 + mb + 1);
        long long q2 = __builtin_nontemporal_load(ew8 + mb + 2);
        long long q3 = __builtin_nontemporal_load(ew8 + mb + 3);
        f32x4 v0 = ldh4(hin + (size_t)(int)q0 * HID + c4);
        f32x4 v1 = ldh4(hin + (size_t)(int)q1 * HID + c4);
        f32x4 v2 = ldh4(hin + (size_t)(int)q2 * HID + c4);
        f32x4 v3 = ldh4(hin + (size_t)(int)q3 * HID + c4);
        acc += __int_as_float((int)(q0 >> 32)) * bnrelu(v0, k1, k2);
        acc += __int_as_float((int)(q1 >> 32)) * bnrelu(v1, k1, k2);
        acc += __int_as_float((int)(q2 >> 32)) * bnrelu(v2, k1, k2);
        acc += __int_as_float((int)(q3 >> 32)) * bnrelu(v3, k1, k2);
      }
      if (j < je) {
        int mb = j + 4 * eg;
        long long q0 = ew8[mb + 0], q1 = ew8[mb + 1];
        long long q2 = ew8[mb + 2], q3 = ew8[mb + 3];
        if (mb + 0 < je) {
          f32x4 v = ldh4(hin + (size_t)(int)q0 * HID + c4);
          acc += __int_as_float((int)(q0 >> 32)) * bnrelu(v, k1, k2);
        }
        if (mb + 1 < je) {
          f32x4 v = ldh4(hin + (size_t)(int)q1 * HID + c4);
          acc += __int_as_float((int)(q1 >> 32)) * bnrelu(v, k1, k2);
        }
        if (mb + 2 < je) {
          f32x4 v = ldh4(hin + (size_t)(int)q2 * HID + c4);
          acc += __int_as_float((int)(q2 >> 32)) * bnrelu(v, k1, k2);
        }
        if (mb + 3 < je) {
          f32x4 v = ldh4(hin + (size_t)(int)q3 * HID + c4);
          acc += __int_as_float((int)(q3 >> 32)) * bnrelu(v, k1, k2);
        }
      }
      acc = xreduce(acc);  // replicated across the 4 groups
      f32x4 hs = bnrelu(__builtin_convertvector(hs16, f32x4), k1, k2);
      f32x4 h0v = __builtin_convertvector(h016v, f32x4);
      f32x4 agg = di * acc + (di * di) * hs;
      f32x4 sval = (1.f - ALPHA) * agg + ALPHA * h0v;
      // split-K conv: group eg computes k in [16*eg, 16*eg+16)
      f32x4 ta = {0.f, 0.f, 0.f, 0.f};
#pragma unroll
      for (int u = 0; u < 4; u++) {
        int kk = 4 * eg + u;
        f32x4 s4;
        s4.x = __shfl(sval.x, kk, 16);
        s4.y = __shfl(sval.y, kk, 16);
        s4.z = __shfl(sval.z, kk, 16);
        s4.w = __shfl(sval.w, kk, 16);
        const f32x4* Wr = (const f32x4*)(Wsh + 4 * kk * HID);
        ta += s4.x * Wr[li] + s4.y * Wr[16 + li] + s4.z * Wr[32 + li] +
              s4.w * Wr[48 + li];
      }
      ta = xreduce(ta);
      f32x4 s2 = (1.f - beta) * sval + beta * ta;
      lsum += s2;
      lsumsq += s2 * s2;
      if (eg == 0) {
        f16x4 st = __builtin_convertvector(s2, f16x4);
        __builtin_nontemporal_store(st, (f16x4*)(sout + (size_t)i * HID + c4));
      }
    }
  }
  if (eg == 0) { red4[0][wid][li] = lsum; red4[1][wid][li] = lsumsq; }
  __syncthreads();
  if (t < 16) {
    f32x4 a = red4[0][0][li] + red4[0][1][li] + red4[0][2][li] + red4[0][3][li];
    f32x4 b = red4[1][0][li] + red4[1][1][li] + red4[1][2][li] + red4[1][3][li];
    atomicAdd(&sumP[(c4 + 0) * 16], a.x);
    atomicAdd(&sumP[(c4 + 1) * 16], a.y);
    atomicAdd(&sumP[(c4 + 2) * 16], a.z);
    atomicAdd(&sumP[(c4 + 3) * 16], a.w);
    atomicAdd(&sumsqP[(c4 + 0) * 16], b.x);
    atomicAdd(&sumsqP[(c4 + 1) * 16], b.y);
    atomicAdd(&sumsqP[(c4 + 2) * 16], b.z);
    atomicAdd(&sumsqP[(c4 + 3) * 16], b.w);
  }
}

// mean/inv-std -> affine form k1 = iv*gamma, k2 = beta - mu*k1; resets sums
__global__ void k_finalize(float* __restrict__ sumP, float* __restrict__ sumsqP,
                           float* __restrict__ mstat,
                           const float* __restrict__ gamma_l,
                           const float* __restrict__ beta_l, int n) {
  int c = threadIdx.x;  // 64 threads
  float s = sumP[c * 16], sq = sumsqP[c * 16];
  float mu = s / (float)n;
  float var = sq / (float)n - mu * mu;
  float iv = rsqrtf(var + BN_EPS);
  float kk1 = iv * gamma_l[c];
  mstat[c] = kk1;
  mstat[64 + c] = beta_l[c] - mu * kk1;
  sumP[c * 16] = 0.f;
  sumsqP[c * 16] = 0.f;
}

// final h = relu(s*k1 + k2): fp16 in, fp32 out (feeds k_out)
__global__ void k_bnfinal(const f16* __restrict__ s,
                          const float* __restrict__ mstat,
                          float* __restrict__ h, int n) {
  int idx = blockIdx.x * NTHREADS + threadIdx.x;  // x4 index
  if (idx < n * (HID / 4)) {
    int c4 = idx & 15;
    f32x4 v = ldh4(s + (size_t)idx * 4);
    f32x4 k1 = ((const f32x4*)mstat)[c4];
    f32x4 k2 = ((const f32x4*)(mstat + 64))[c4];
    v = v * k1 + k2;
    v.x = fmaxf(v.x, 0.f); v.y = fmaxf(v.y, 0.f);
    v.z = fmaxf(v.z, 0.f); v.w = fmaxf(v.w, 0.f);
    ((f32x4*)h)[idx] = v;
  }
}

// out = h @ W_out + b_out
__global__ __launch_bounds__(NTHREADS) void k_out(
    const float* __restrict__ h, const float* __restrict__ Wout,
    const float* __restrict__ bout, float* __restrict__ out, int n) {
  __shared__ float Ws[HID * OUT_C];
  __shared__ float bs[OUT_C];
  int t = threadIdx.x;
  for (int m = t; m < HID * OUT_C; m += NTHREADS) Ws[m] = Wout[m];
  if (t < OUT_C) bs[t] = bout[t];
  __syncthreads();
  int idx = blockIdx.x * NTHREADS + t;
  if (idx < n * OUT_C) {
    int row = idx / OUT_C;
    int c = idx - row * OUT_C;
    float acc = bs[c];
    const float4* h4 = (const float4*)(h + (size_t)row * HID);
    for (int kk = 0; kk < HID / 4; kk++) {
      float4 a = h4[kk];
      int k = kk * 4;
      acc += a.x * Ws[(k + 0) * OUT_C + c] + a.y * Ws[(k + 1) * OUT_C + c] +
             a.z * Ws[(k + 2) * OUT_C + c] + a.w * Ws[(k + 3) * OUT_C + c];
    }
    out[idx] = acc;
  }
}

// ---------------- host ----------------

extern "C" void kernel_launch(void* const* d_in, const int* in_sizes, int n_in,
                              void* d_out, int out_size, void* d_ws, size_t ws_size,
                              hipStream_t stream) {
  const float* x = (const float*)d_in[0];
  const int* ei = (const int*)d_in[1];
  const float* W0 = (const float*)d_in[2];
  const float* b0 = (const float*)d_in[3];
  const float* convW = (const float*)d_in[4];
  const float* bn_gamma = (const float*)d_in[5];
  const float* bn_beta = (const float*)d_in[6];
  const float* W_out = (const float*)d_in[7];
  const float* b_out = (const float*)d_in[8];
  float* out = (float*)d_out;

  int n = in_sizes[0] / IN_C;   // 100000
  int E = in_sizes[1] / 2;      // 1600000
  const int* row = ei;
  const int* col = ei + E;

  char* w = (char*)d_ws;
  auto alloc = [&](size_t bytes) {
    char* p = w;
    w += (bytes + 255) & ~(size_t)255;
    return p;
  };
  float* dinv    = (float*)alloc((size_t)n * 4);
  int*   cnt     = (int*)alloc((size_t)n * 4);
  int*   offs    = (int*)alloc((size_t)(n + 1) * 4);
  int*   cur     = (int*)alloc((size_t)n * 4);
  int*   partials= (int*)alloc(512 * 4);
  int2*  ew      = (int2*)alloc((size_t)(E + 16) * 8);  // +16 pad records
  f16*   h016    = (f16*)alloc((size_t)n * HID * 2);
  f16*   sA      = (f16*)alloc((size_t)n * HID * 2);
  f16*   sB      = (f16*)alloc((size_t)n * HID * 2);
  float* hb      = (float*)alloc((size_t)n * HID * 4);  // fp32 input to k_out
  float* sumP    = (float*)alloc(1024 * 4);
  float* sumsqP  = (float*)alloc(1024 * 4);
  float* mstat   = (float*)alloc(128 * 4);

  int gN = (n + NTHREADS - 1) / NTHREADS;   // 391
  int gE = (E + NTHREADS - 1) / NTHREADS;   // 6250

  k_zero<<<gN, NTHREADS, 0, stream>>>(cnt, sumP, sumsqP, mstat, ew + E, n);
  k_hist<<<gE, NTHREADS, 0, stream>>>(col, cnt, E);
  k_dinv<<<gN, NTHREADS, 0, stream>>>(cnt, dinv, n);
  k_scan1<<<gN, NTHREADS, 0, stream>>>(cnt, offs, partials, n);
  k_scan2<<<1, 512, 0, stream>>>(partials, gN);
  k_scan3<<<gN, NTHREADS, 0, stream>>>(offs, cur, partials, n, E);
  k_fill<<<gE, NTHREADS, 0, stream>>>(row, col, dinv, cur, ew, E);

  k_gemm0<<<1024, NTHREADS, 0, stream>>>(x, W0, b0, h016, n);

  // layer l: input = (l==0 ? h016 : previous out), BN_{l-1} fused via mstat
  for (int l = 0; l < N_LAYERS; l++) {
    float beta = logf(0.5f / (float)(l + 1) + 1.0f);
    const f16* inp = (l == 0) ? h016 : ((l & 1) ? sA : sB);
    f16* outp = (l & 1) ? sB : sA;
    k_layer<<<2048, NTHREADS, 0, stream>>>(inp, h016, dinv, offs, ew,
                                           convW + (size_t)l * HID * HID, mstat,
                                           outp, sumP, sumsqP, beta, n);
    k_finalize<<<1, 64, 0, stream>>>(sumP, sumsqP, mstat,
                                     bn_gamma + l * HID, bn_beta + l * HID, n);
  }

  // s_7 lives in sB; h = relu(BN_7(s_7)) in fp32, then output GEMM
  k_bnfinal<<<(n * (HID / 4) + NTHREADS - 1) / NTHREADS, NTHREADS, 0, stream>>>(
      sB, mstat, hb, n);
  k_out<<<((size_t)n * OUT_C + NTHREADS - 1) / NTHREADS, NTHREADS, 0, stream>>>(
      hb, W_out, b_out, out, n);
}